// Round 4
// baseline (649.999 us; speedup 1.0000x reference)
//
#include <hip/hip_runtime.h>
#include <math.h>

// Problem constants
#define B_    64
#define S_    2048
#define E_    300
#define H_    150
#define C_    34
#define NROWS 50000
#define SLOT  32        // max tokens per embedding row over whole batch.
                        // Poisson(lambda=131072/50000=2.62): P(X>=32) ~ 1e-27/row.
#define PBLK  256       // stream-kernel blocks (each owns a row range)
#define RPB   ((NROWS + PBLK - 1) / PBLK)   // 196 rows/block
#define PJ    (B_ * E_ + B_)                // 19264 floats per partial slice

// ---------- bucket build ----------
__global__ __launch_bounds__(256) void zero_cnt(int* __restrict__ cnt) {
    int i = blockIdx.x * 256 + threadIdx.x;
    if (i < NROWS) cnt[i] = 0;
}

// Fused count+scatter: entb[r*SLOT + slot] = batch index b of each token.
__global__ __launch_bounds__(256) void scatter_tokens(
    const int* __restrict__ x, int* __restrict__ cnt,
    unsigned char* __restrict__ entb)
{
    int i = blockIdx.x * 256 + threadIdx.x;      // token id
    if (i >= B_ * S_) return;
    int r = x[i];
    int b = i >> 11;                             // i / S_
    int slot = atomicAdd(&cnt[r], 1);
    if (slot < SLOT) entb[r * SLOT + slot] = (unsigned char)b;
}

// ---------- stage 1 stream ----------
// Row layout per wave: lane i holds elements e = i + 64k, k=0..4 (k=4: i<44).
// Score per row: s1 = scale * q.row (b-independent). Shift-free softmax:
// accumulate hp[b] += exp(s1)*row, lp[b] += exp(s1) per bucket entry.
__global__ __launch_bounds__(256, 2) void stage1_stream(
    const float* __restrict__ emb, const float* __restrict__ query,
    const int* __restrict__ cnt, const unsigned char* __restrict__ entb,
    float* __restrict__ p_h)
{
    __shared__ float hp[B_ * E_];   // 76.8 KB -> 2 blocks/CU
    __shared__ float lp[B_];
    const int tid = threadIdx.x, w = tid >> 6, lane = tid & 63;
    for (int j = tid; j < B_ * E_; j += 256) hp[j] = 0.f;
    if (tid < B_) lp[tid] = 0.f;
    __syncthreads();

    const float scale = 0.057735026918962584f;   // 1/sqrt(300)
    float q[5];
    #pragma unroll
    for (int k = 0; k < 5; ++k) {
        int e = lane + 64 * k;
        q[k] = (e < E_) ? query[e] * scale : 0.f;
    }

    const int r0    = blockIdx.x * RPB;
    const int r_end = min(r0 + RPB, NROWS);

    // two rows per iteration: 10 loads in flight before any dependent use
    for (int r = r0 + w; r < r_end; r += 8) {
        const int  rb   = r + 4;
        const bool has2 = (rb < r_end);
        const float* ra = emb + (size_t)r * E_;
        const float* rbp = emb + (size_t)(has2 ? rb : r) * E_;
        float rv[5], rv2[5];
        #pragma unroll
        for (int k = 0; k < 4; ++k) {
            rv[k]  = ra[lane + 64 * k];
            rv2[k] = rbp[lane + 64 * k];
        }
        { int e = lane + 256;
          rv[4]  = (e < E_) ? ra[e]  : 0.f;
          rv2[4] = (e < E_) ? rbp[e] : 0.f; }
        int n1 = min(cnt[r], SLOT);
        int n2 = has2 ? min(cnt[rb], SLOT) : 0;

        if (n1 > 0) {
            float d = rv[0]*q[0] + rv[1]*q[1] + rv[2]*q[2] + rv[3]*q[3] + rv[4]*q[4];
            #pragma unroll
            for (int off = 32; off > 0; off >>= 1) d += __shfl_xor(d, off);
            const float wg = __expf(d);
            for (int j = 0; j < n1; ++j) {
                const int b = entb[r * SLOT + j];
                float* dst = hp + b * E_;
                #pragma unroll
                for (int k = 0; k < 5; ++k) {
                    int e = lane + 64 * k;
                    if (e < E_) atomicAdd(&dst[e], wg * rv[k]);
                }
                if (lane == 0) atomicAdd(&lp[b], wg);
            }
        }
        if (n2 > 0) {
            float d = rv2[0]*q[0] + rv2[1]*q[1] + rv2[2]*q[2] + rv2[3]*q[3] + rv2[4]*q[4];
            #pragma unroll
            for (int off = 32; off > 0; off >>= 1) d += __shfl_xor(d, off);
            const float wg = __expf(d);
            for (int j = 0; j < n2; ++j) {
                const int b = entb[rb * SLOT + j];
                float* dst = hp + b * E_;
                #pragma unroll
                for (int k = 0; k < 5; ++k) {
                    int e = lane + 64 * k;
                    if (e < E_) atomicAdd(&dst[e], wg * rv2[k]);
                }
                if (lane == 0) atomicAdd(&lp[b], wg);
            }
        }
    }
    __syncthreads();
    float* o = p_h + (size_t)blockIdx.x * PJ;
    for (int j = tid; j < B_ * E_; j += 256) o[j] = hp[j];
    if (tid < B_) o[B_ * E_ + tid] = lp[tid];
}

// ---------- stage 2 stream ----------
// Per bucket entry: s2 = v2[b].row (per-entry dot, v2 L2-hot), then same accum.
__global__ __launch_bounds__(256, 2) void stage2_stream(
    const float* __restrict__ emb, const float* __restrict__ v2,
    const int* __restrict__ cnt, const unsigned char* __restrict__ entb,
    float* __restrict__ p_h)
{
    __shared__ float hp[B_ * E_];
    __shared__ float lp[B_];
    const int tid = threadIdx.x, w = tid >> 6, lane = tid & 63;
    for (int j = tid; j < B_ * E_; j += 256) hp[j] = 0.f;
    if (tid < B_) lp[tid] = 0.f;
    __syncthreads();

    const int r0    = blockIdx.x * RPB;
    const int r_end = min(r0 + RPB, NROWS);

    for (int r = r0 + w; r < r_end; r += 8) {
        const int  rb   = r + 4;
        const bool has2 = (rb < r_end);
        const float* ra  = emb + (size_t)r * E_;
        const float* rbp = emb + (size_t)(has2 ? rb : r) * E_;
        float rv[5], rv2[5];
        #pragma unroll
        for (int k = 0; k < 4; ++k) {
            rv[k]  = ra[lane + 64 * k];
            rv2[k] = rbp[lane + 64 * k];
        }
        { int e = lane + 256;
          rv[4]  = (e < E_) ? ra[e]  : 0.f;
          rv2[4] = (e < E_) ? rbp[e] : 0.f; }
        int n1 = min(cnt[r], SLOT);
        int n2 = has2 ? min(cnt[rb], SLOT) : 0;

        for (int j = 0; j < n1; ++j) {
            const int b = entb[r * SLOT + j];
            const float* vb = v2 + b * E_;
            float d = rv[0]*vb[lane] + rv[1]*vb[lane+64] + rv[2]*vb[lane+128]
                    + rv[3]*vb[lane+192];
            if (lane < 44) d += rv[4]*vb[lane+256];
            #pragma unroll
            for (int off = 32; off > 0; off >>= 1) d += __shfl_xor(d, off);
            const float wg = __expf(d);
            float* dst = hp + b * E_;
            #pragma unroll
            for (int k = 0; k < 5; ++k) {
                int e = lane + 64 * k;
                if (e < E_) atomicAdd(&dst[e], wg * rv[k]);
            }
            if (lane == 0) atomicAdd(&lp[b], wg);
        }
        for (int j = 0; j < n2; ++j) {
            const int b = entb[rb * SLOT + j];
            const float* vb = v2 + b * E_;
            float d = rv2[0]*vb[lane] + rv2[1]*vb[lane+64] + rv2[2]*vb[lane+128]
                    + rv2[3]*vb[lane+192];
            if (lane < 44) d += rv2[4]*vb[lane+256];
            #pragma unroll
            for (int off = 32; off > 0; off >>= 1) d += __shfl_xor(d, off);
            const float wg = __expf(d);
            float* dst = hp + b * E_;
            #pragma unroll
            for (int k = 0; k < 5; ++k) {
                int e = lane + 64 * k;
                if (e < E_) atomicAdd(&dst[e], wg * rv2[k]);
            }
            if (lane == 0) atomicAdd(&lp[b], wg);
        }
    }
    __syncthreads();
    float* o = p_h + (size_t)blockIdx.x * PJ;
    for (int j = tid; j < B_ * E_; j += 256) o[j] = hp[j];
    if (tid < B_) o[B_ * E_ + tid] = lp[tid];
}

// ---------- reduce 256 partial slices -> raw sums (h-unnorm ++ l), 19264 j's
__global__ __launch_bounds__(256) void reduce_parts(
    const float* __restrict__ p_h, float* __restrict__ acc_out)
{
    const int j  = blockIdx.x * 64 + (threadIdx.x & 63);   // 301 blocks * 64 = 19264
    const int pc = threadIdx.x >> 6;                        // 0..3
    float a = 0.f;
    for (int p = pc; p < PBLK; p += 4)
        a += p_h[(size_t)p * PJ + j];
    __shared__ float s[4][64];
    s[pc][threadIdx.x & 63] = a;
    __syncthreads();
    if (pc == 0)
        acc_out[j] = s[0][threadIdx.x] + s[1][threadIdx.x]
                   + s[2][threadIdx.x] + s[3][threadIdx.x];
}

// ---------- h1 = acc/l ; v2 = (h1 @ W) @ W^T ----------
__global__ __launch_bounds__(320) void qv_kernel(
    const float* __restrict__ acc, const float* __restrict__ W,
    float* __restrict__ h1out, float* __restrict__ v2out)
{
    const int b = blockIdx.x, tid = threadIdx.x;
    __shared__ float sh[E_], sq[H_];
    const float linv = 1.f / acc[B_ * E_ + b];
    if (tid < E_) {
        float h = acc[b * E_ + tid] * linv;
        sh[tid] = h;
        h1out[b * E_ + tid] = h;
    }
    __syncthreads();
    if (tid < H_) {
        float a = 0.f;
        for (int e = 0; e < E_; ++e) a += sh[e] * W[e * H_ + tid];
        sq[tid] = a;
    }
    __syncthreads();
    if (tid < E_) {
        float a = 0.f;
        const float* wr = W + (size_t)tid * H_;
        for (int h = 0; h < H_; ++h) a += sq[h] * wr[h];
        v2out[b * E_ + tid] = a;
    }
}

// ---------- h2 = acc2/l2 ; out = [h1;h2] @ Wout + bias ----------
__global__ __launch_bounds__(320) void scores_kernel(
    const float* __restrict__ acc2, const float* __restrict__ h1,
    const float* __restrict__ Wout, const float* __restrict__ bias,
    float* __restrict__ out)
{
    const int b = blockIdx.x, tid = threadIdx.x;
    const int w = tid >> 6, lane = tid & 63;
    __shared__ float hh[2 * E_];
    const float linv = 1.f / acc2[B_ * E_ + b];
    if (tid < E_) {
        hh[tid]      = h1[b * E_ + tid];
        hh[E_ + tid] = acc2[b * E_ + tid] * linv;
    }
    __syncthreads();
    for (int c = w; c < C_; c += 5) {
        float p = 0.f;
        for (int e = lane; e < 2 * E_; e += 64)
            p += hh[e] * Wout[(size_t)e * C_ + c];
        #pragma unroll
        for (int off = 32; off > 0; off >>= 1) p += __shfl_xor(p, off);
        if (lane == 0) out[b * C_ + c] = p + bias[c];
    }
}

extern "C" void kernel_launch(void* const* d_in, const int* in_sizes, int n_in,
                              void* d_out, int out_size, void* d_ws, size_t ws_size,
                              hipStream_t stream) {
    const int*   x     = (const int*)  d_in[0];   // [64,2048]
    const float* emb   = (const float*)d_in[1];   // [50000,300]
    const float* query = (const float*)d_in[2];   // [1,300]
    const float* Watt  = (const float*)d_in[3];   // [300,150]
    const float* Wout  = (const float*)d_in[4];   // [600,34]
    const float* bias  = (const float*)d_in[5];   // [34]
    float* out = (float*)d_out;                   // [64,34]

    // Workspace layout (bytes->floats), ~22 MB total
    char* wsb = (char*)d_ws;
    int*           cnt   = (int*)wsb;                          // 50000 ints
    unsigned char* entb  = (unsigned char*)(wsb + 50048 * 4);  // 50000*32 B
    float*         p_h   = (float*)(wsb + 50048 * 4 + NROWS * SLOT); // 256*19264
    float*         acc1  = p_h + (size_t)PBLK * PJ;            // 19264
    float*         acc2  = acc1 + PJ;                          // 19264
    float*         h1    = acc2 + PJ;                          // 19200
    float*         v2    = h1 + B_ * E_;                       // 19200

    zero_cnt      <<<(NROWS + 255) / 256, 256, 0, stream>>>(cnt);
    scatter_tokens<<<(B_ * S_) / 256,     256, 0, stream>>>(x, cnt, entb);
    stage1_stream <<<PBLK, 256, 0, stream>>>(emb, query, cnt, entb, p_h);
    reduce_parts  <<<PJ / 64, 256, 0, stream>>>(p_h, acc1);
    qv_kernel     <<<B_, 320, 0, stream>>>(acc1, Watt, h1, v2);
    stage2_stream <<<PBLK, 256, 0, stream>>>(emb, v2, cnt, entb, p_h);
    reduce_parts  <<<PJ / 64, 256, 0, stream>>>(p_h, acc2);
    scores_kernel <<<B_, 320, 0, stream>>>(acc2, h1, Wout, bias, out);
}

// Round 5
// 404.303 us; speedup vs baseline: 1.6077x; 1.6077x over previous
//
#include <hip/hip_runtime.h>
#include <math.h>

// Problem constants
#define B_  64
#define S_  2048
#define E_  300
#define H_  150
#define C_  34
#define CHUNK 128
#define NCHUNK (S_ / CHUNK)   // 16
#define PJ (B_ * E_ + B_)     // accumulator: h-sums [B*E] then l-sums [B]

// Zero both stage accumulators (ws is 0xAA-poisoned before every call)
__global__ __launch_bounds__(256) void zero_acc(float* __restrict__ acc) {
    int i = blockIdx.x * 256 + threadIdx.x;
    if (i < 2 * PJ) acc[i] = 0.f;
}

// Gather pass, SHIFT-FREE softmax (validated exact in round 4: scores are
// small; exp never overflows; absmax was 0.0). Wave w handles tokens w+4k of
// its 128-token chunk, 4 tokens/group, double-buffered row prefetch.
// Epilogue: 4-wave LDS combine, then atomicAdd 301 values into global acc.
__global__ __launch_bounds__(256, 4) void attn_gather(
    const int* __restrict__ x, const float* __restrict__ emb,
    const float* __restrict__ qmat, int q_stride, float scale,
    float* __restrict__ acc)
{
    const int b     = blockIdx.y;
    const int chunk = blockIdx.x;
    const int tid   = threadIdx.x;
    const int w     = tid >> 6;
    const int lane  = tid & 63;

    // Per-lane query fragment (pre-scaled): float4 slot lane + slot 64+lane
    const float4* qp = (const float4*)(qmat + (size_t)b * q_stride);
    float4 q0 = qp[lane];
    float4 q1 = make_float4(0.f, 0.f, 0.f, 0.f);
    if (lane < 11) q1 = qp[64 + lane];
    q0.x *= scale; q0.y *= scale; q0.z *= scale; q0.w *= scale;
    q1.x *= scale; q1.y *= scale; q1.z *= scale; q1.w *= scale;

    // Wave's 32 token indices in lanes 0..31
    const int base = b * S_ + chunk * CHUNK;
    int myidx = 0;
    if (lane < 32) myidx = x[base + w + 4 * lane];

    float  l  = 0.f;
    float4 a0 = make_float4(0.f, 0.f, 0.f, 0.f);
    float4 a1 = make_float4(0.f, 0.f, 0.f, 0.f);

    float4 r0[2][4], r1[2][4];

    // prefetch group 0
    #pragma unroll
    for (int t = 0; t < 4; ++t) {
        const int row = __shfl(myidx, t);
        const float4* rp = (const float4*)(emb + (size_t)row * E_);
        r0[0][t] = rp[lane];
        r1[0][t] = make_float4(0.f, 0.f, 0.f, 0.f);
        if (lane < 11) r1[0][t] = rp[64 + lane];
    }

    #pragma unroll
    for (int g = 0; g < 8; ++g) {
        const int cur = g & 1;
        // prefetch next group while current computes
        if (g < 7) {
            const int nxt = cur ^ 1;
            #pragma unroll
            for (int t = 0; t < 4; ++t) {
                const int row = __shfl(myidx, 4 * (g + 1) + t);
                const float4* rp = (const float4*)(emb + (size_t)row * E_);
                r0[nxt][t] = rp[lane];
                r1[nxt][t] = make_float4(0.f, 0.f, 0.f, 0.f);
                if (lane < 11) r1[nxt][t] = rp[64 + lane];
            }
        }
        // 4 dots
        float d[4];
        #pragma unroll
        for (int t = 0; t < 4; ++t)
            d[t] = q0.x * r0[cur][t].x + q0.y * r0[cur][t].y
                 + q0.z * r0[cur][t].z + q0.w * r0[cur][t].w
                 + q1.x * r1[cur][t].x + q1.y * r1[cur][t].y
                 + q1.z * r1[cur][t].z + q1.w * r1[cur][t].w;
        // 4 interleaved butterfly reduces
        #pragma unroll
        for (int off = 32; off > 0; off >>= 1) {
            #pragma unroll
            for (int t = 0; t < 4; ++t) d[t] += __shfl_xor(d[t], off);
        }
        // shift-free accumulate
        const float w0 = __expf(d[0]), w1 = __expf(d[1]);
        const float w2 = __expf(d[2]), w3 = __expf(d[3]);
        l += (w0 + w1) + (w2 + w3);
        a0.x += w0 * r0[cur][0].x + w1 * r0[cur][1].x + w2 * r0[cur][2].x + w3 * r0[cur][3].x;
        a0.y += w0 * r0[cur][0].y + w1 * r0[cur][1].y + w2 * r0[cur][2].y + w3 * r0[cur][3].y;
        a0.z += w0 * r0[cur][0].z + w1 * r0[cur][1].z + w2 * r0[cur][2].z + w3 * r0[cur][3].z;
        a0.w += w0 * r0[cur][0].w + w1 * r0[cur][1].w + w2 * r0[cur][2].w + w3 * r0[cur][3].w;
        a1.x += w0 * r1[cur][0].x + w1 * r1[cur][1].x + w2 * r1[cur][2].x + w3 * r1[cur][3].x;
        a1.y += w0 * r1[cur][0].y + w1 * r1[cur][1].y + w2 * r1[cur][2].y + w3 * r1[cur][3].y;
        a1.z += w0 * r1[cur][0].z + w1 * r1[cur][1].z + w2 * r1[cur][2].z + w3 * r1[cur][3].z;
        a1.w += w0 * r1[cur][0].w + w1 * r1[cur][1].w + w2 * r1[cur][2].w + w3 * r1[cur][3].w;
    }

    // 4-wave LDS combine, then global atomic reduce (16 chunks -> acc[b])
    __shared__ float sl[4];
    __shared__ __align__(16) float sacc[4][304];
    ((float4*)sacc[w])[lane] = a0;
    if (lane < 11) ((float4*)sacc[w])[64 + lane] = a1;
    if (lane == 0) sl[w] = l;
    __syncthreads();

    for (int j = tid; j < E_; j += 256)   // E_=300 > 256: must loop
        atomicAdd(&acc[b * E_ + j],
                  (sacc[0][j] + sacc[1][j]) + (sacc[2][j] + sacc[3][j]));
    if (tid == 0)
        atomicAdd(&acc[B_ * E_ + b], (sl[0] + sl[1]) + (sl[2] + sl[3]));
}

// h1 = accH/accL ; v2 = (h1 @ W) @ W^T  (k2-elimination trick)
__global__ __launch_bounds__(320) void qv_kernel(
    const float* __restrict__ acc, const float* __restrict__ W,
    float* __restrict__ h1out, float* __restrict__ v2out)
{
    const int b = blockIdx.x, tid = threadIdx.x;
    __shared__ float sh[E_], sq[H_];
    const float linv = 1.f / acc[B_ * E_ + b];
    if (tid < E_) {
        float h = acc[b * E_ + tid] * linv;
        sh[tid] = h;
        h1out[b * E_ + tid] = h;
    }
    __syncthreads();
    if (tid < H_) {
        float a = 0.f;
        for (int e = 0; e < E_; ++e) a += sh[e] * W[e * H_ + tid];
        sq[tid] = a;
    }
    __syncthreads();
    if (tid < E_) {
        float a = 0.f;
        const float* wr = W + (size_t)tid * H_;
        for (int h = 0; h < H_; ++h) a += sq[h] * wr[h];
        v2out[b * E_ + tid] = a;
    }
}

// h2 = acc2H/acc2L ; out = [h1;h2] @ Wout + bias
__global__ __launch_bounds__(320) void scores_kernel(
    const float* __restrict__ acc2, const float* __restrict__ h1,
    const float* __restrict__ Wout, const float* __restrict__ bias,
    float* __restrict__ out)
{
    const int b = blockIdx.x, tid = threadIdx.x;
    const int w = tid >> 6, lane = tid & 63;
    __shared__ float hh[2 * E_];
    const float linv = 1.f / acc2[B_ * E_ + b];
    if (tid < E_) {
        hh[tid]      = h1[b * E_ + tid];
        hh[E_ + tid] = acc2[b * E_ + tid] * linv;
    }
    __syncthreads();
    for (int c = w; c < C_; c += 5) {
        float p = 0.f;
        for (int e = lane; e < 2 * E_; e += 64)
            p += hh[e] * Wout[(size_t)e * C_ + c];
        #pragma unroll
        for (int off = 32; off > 0; off >>= 1) p += __shfl_xor(p, off);
        if (lane == 0) out[b * C_ + c] = p + bias[c];
    }
}

extern "C" void kernel_launch(void* const* d_in, const int* in_sizes, int n_in,
                              void* d_out, int out_size, void* d_ws, size_t ws_size,
                              hipStream_t stream) {
    const int*   x     = (const int*)  d_in[0];   // [64,2048]
    const float* emb   = (const float*)d_in[1];   // [50000,300]
    const float* query = (const float*)d_in[2];   // [1,300]
    const float* Watt  = (const float*)d_in[3];   // [300,150]
    const float* Wout  = (const float*)d_in[4];   // [600,34]
    const float* bias  = (const float*)d_in[5];   // [34]
    float* out = (float*)d_out;                   // [64,34]

    // Workspace (floats): acc1[PJ] ++ acc2[PJ] ++ h1 ++ v2  (~300 KB)
    float* acc1 = (float*)d_ws;
    float* acc2 = acc1 + PJ;
    float* h1   = acc2 + PJ;
    float* v2   = h1 + B_ * E_;

    const float scale1 = 1.0f / sqrtf((float)E_);
    dim3 grid(NCHUNK, B_), blk(256);

    zero_acc<<<(2 * PJ + 255) / 256, 256, 0, stream>>>(acc1);  // zeros acc1+acc2
    // Stage 1: broadcast query (stride 0), scaled by 1/sqrt(E)
    attn_gather<<<grid, blk, 0, stream>>>(x, emb, query, 0, scale1, acc1);
    qv_kernel<<<B_, 320, 0, stream>>>(acc1, Watt, h1, v2);
    // Stage 2: per-b query v2, no scale
    attn_gather<<<grid, blk, 0, stream>>>(x, emb, v2, E_, 1.0f, acc2);
    scores_kernel<<<B_, 320, 0, stream>>>(acc2, h1, Wout, bias, out);
}

// Round 6
// 181.053 us; speedup vs baseline: 3.5901x; 2.2331x over previous
//
#include <hip/hip_runtime.h>
#include <math.h>

// Problem constants
#define B_  64
#define S_  2048
#define E_  300
#define EP  320            // padded row length: 320 bf16 = 640 B = 5 x 128B sectors
#define H_  150
#define C_  34
#define CHUNK 128
#define NCHUNK (S_ / CHUNK)   // 16

// Convert emb (fp32, 1200B rows) -> bf16 rows padded to 640B, 128B-aligned.
// Block 3125 also prepares the padded+pre-scaled stage-1 query.
__global__ __launch_bounds__(320) void conv_bf16(
    const float* __restrict__ emb, const float* __restrict__ query,
    unsigned short* __restrict__ ebf, float* __restrict__ qpad)
{
    const int tid = threadIdx.x;
    if (blockIdx.x == 3125) {           // 3125*16 = 50000 rows handled below
        const float scale = 0.057735026918962584f;   // 1/sqrt(300)
        qpad[tid] = (tid < E_) ? query[tid] * scale : 0.f;
        return;
    }
    const int rbase = blockIdx.x * 16;
    for (int k = 0; k < 16; ++k) {
        const int r = rbase + k;
        float v = (tid < E_) ? emb[(size_t)r * E_ + tid] : 0.f;
        unsigned int u = __float_as_uint(v);
        // round-to-nearest-even bf16
        unsigned short us = (unsigned short)((u + 0x7FFFu + ((u >> 16) & 1u)) >> 16);
        ebf[(size_t)r * EP + tid] = us;
    }
}

__device__ __forceinline__ float bflo(unsigned int u) { return __uint_as_float(u << 16); }
__device__ __forceinline__ float bfhi(unsigned int u) { return __uint_as_float(u & 0xFFFF0000u); }

// Gather pass over bf16 rows, shift-free softmax (validated exact r4/r5).
// Wave w handles tokens w+4k of its 128-token chunk; lanes 0..39 each load a
// 16B (8-bf16) slot of the 640B row -> ONE dwordx4 instr per row.
// Per 4-token group: 4 loads in flight, dots, interleaved butterflies, exp,
// accumulate a[8] fp32/lane (unpack recomputed in the FMA pass to keep VGPRs low).
// Epilogue: 4-wave LDS combine -> per-chunk partial (h[300], l) in ws.
__global__ __launch_bounds__(256, 4) void attn_bf16(
    const int* __restrict__ x, const unsigned short* __restrict__ ebf,
    const float* __restrict__ qmat, int q_stride,
    float* __restrict__ h_part, float* __restrict__ l_part)
{
    const int b     = blockIdx.y;
    const int chunk = blockIdx.x;
    const int tid   = threadIdx.x;
    const int w     = tid >> 6;
    const int lane  = tid & 63;
    const bool act  = (lane < 40);     // 40 lanes x 8 elems = 320

    // query fragment: elems 8*lane .. 8*lane+7 (qmat rows padded to EP, zero tail)
    float qf[8];
    {
        const float4* qp = (const float4*)(qmat + (size_t)b * q_stride);
        float4 qa = make_float4(0.f, 0.f, 0.f, 0.f), qb = qa;
        if (act) { qa = qp[2 * lane]; qb = qp[2 * lane + 1]; }
        qf[0] = qa.x; qf[1] = qa.y; qf[2] = qa.z; qf[3] = qa.w;
        qf[4] = qb.x; qf[5] = qb.y; qf[6] = qb.z; qf[7] = qb.w;
    }

    const int base = b * S_ + chunk * CHUNK;
    int myidx = 0;
    if (lane < 32) myidx = x[base + w + 4 * lane];

    float l = 0.f;
    float a[8];
    #pragma unroll
    for (int k = 0; k < 8; ++k) a[k] = 0.f;

    for (int g = 0; g < 8; ++g) {
        uint4 rv[4];
        #pragma unroll
        for (int t = 0; t < 4; ++t) {
            const int row = __shfl(myidx, 4 * g + t);
            rv[t] = make_uint4(0u, 0u, 0u, 0u);
            if (act) rv[t] = ((const uint4*)(ebf + (size_t)row * EP))[lane];
        }
        // dots (unpack on the fly; lanes >=40 contribute 0)
        float d[4];
        #pragma unroll
        for (int t = 0; t < 4; ++t) {
            const unsigned int* u = (const unsigned int*)&rv[t];
            float s = 0.f;
            #pragma unroll
            for (int j = 0; j < 4; ++j) {
                s += qf[2 * j]     * bflo(u[j]);
                s += qf[2 * j + 1] * bfhi(u[j]);
            }
            d[t] = s;
        }
        // 4 interleaved butterfly reduces
        #pragma unroll
        for (int off = 32; off > 0; off >>= 1) {
            #pragma unroll
            for (int t = 0; t < 4; ++t) d[t] += __shfl_xor(d[t], off);
        }
        // shift-free weights
        float wt[4];
        #pragma unroll
        for (int t = 0; t < 4; ++t) wt[t] = __expf(d[t]);
        l += (wt[0] + wt[1]) + (wt[2] + wt[3]);
        // accumulate (re-unpack; keeps live VGPRs low)
        #pragma unroll
        for (int t = 0; t < 4; ++t) {
            const unsigned int* u = (const unsigned int*)&rv[t];
            #pragma unroll
            for (int j = 0; j < 4; ++j) {
                a[2 * j]     += wt[t] * bflo(u[j]);
                a[2 * j + 1] += wt[t] * bfhi(u[j]);
            }
        }
    }

    // 4-wave combine in LDS, write per-chunk partial to ws
    __shared__ float sl[4];
    __shared__ __align__(16) float sacc[4][EP];
    if (act) {
        float4* dst = (float4*)&sacc[w][8 * lane];
        dst[0] = make_float4(a[0], a[1], a[2], a[3]);
        dst[1] = make_float4(a[4], a[5], a[6], a[7]);
    }
    if (lane == 0) sl[w] = l;
    __syncthreads();

    const int pi = b * NCHUNK + chunk;
    for (int j = tid; j < E_; j += 256)       // E_=300 > 256: loop
        h_part[(size_t)pi * E_ + j] =
            (sacc[0][j] + sacc[1][j]) + (sacc[2][j] + sacc[3][j]);
    if (tid == 0) l_part[pi] = (sl[0] + sl[1]) + (sl[2] + sl[3]);
}

// combine chunk partials -> h1[b]; v2[b] = (h1 @ W) @ W^T, padded to EP
__global__ __launch_bounds__(320) void combine_qv(
    const float* __restrict__ h_part, const float* __restrict__ l_part,
    const float* __restrict__ W, float* __restrict__ h1out,
    float* __restrict__ v2out)
{
    const int b = blockIdx.x, tid = threadIdx.x;
    __shared__ float sh[E_], sq[H_];
    float L = 0.f;
    #pragma unroll
    for (int c = 0; c < NCHUNK; ++c) L += l_part[b * NCHUNK + c];
    if (tid < E_) {
        float s = 0.f;
        #pragma unroll
        for (int c = 0; c < NCHUNK; ++c)
            s += h_part[((size_t)b * NCHUNK + c) * E_ + tid];
        float h = s / L;
        sh[tid] = h;
        h1out[b * E_ + tid] = h;
    }
    __syncthreads();
    if (tid < H_) {
        float acc = 0.f;
        for (int e = 0; e < E_; ++e) acc += sh[e] * W[e * H_ + tid];
        sq[tid] = acc;
    }
    __syncthreads();
    // padded v2 row (elems 300..319 = 0) so attn's float4 q-frag loads stay in-bounds
    float acc = 0.f;
    if (tid < E_) {
        const float* wr = W + (size_t)tid * H_;
        for (int h = 0; h < H_; ++h) acc += sq[h] * wr[h];
    }
    v2out[b * EP + tid] = (tid < E_) ? acc : 0.f;
}

// combine chunk partials -> h2[b]; out = [h1;h2] @ Wout + bias
__global__ __launch_bounds__(320) void combine_scores(
    const float* __restrict__ h_part, const float* __restrict__ l_part,
    const float* __restrict__ h1, const float* __restrict__ Wout,
    const float* __restrict__ bias, float* __restrict__ out)
{
    const int b = blockIdx.x, tid = threadIdx.x;
    const int w = tid >> 6, lane = tid & 63;
    __shared__ float hh[2 * E_];
    float L = 0.f;
    #pragma unroll
    for (int c = 0; c < NCHUNK; ++c) L += l_part[b * NCHUNK + c];
    if (tid < E_) {
        float s = 0.f;
        #pragma unroll
        for (int c = 0; c < NCHUNK; ++c)
            s += h_part[((size_t)b * NCHUNK + c) * E_ + tid];
        hh[tid]      = h1[b * E_ + tid];
        hh[E_ + tid] = s / L;
    }
    __syncthreads();
    for (int c = w; c < C_; c += 5) {     // 5 waves cover 34 classes
        float p = 0.f;
        for (int e = lane; e < 2 * E_; e += 64)
            p += hh[e] * Wout[(size_t)e * C_ + c];
        #pragma unroll
        for (int off = 32; off > 0; off >>= 1) p += __shfl_xor(p, off);
        if (lane == 0) out[b * C_ + c] = p + bias[c];
    }
}

extern "C" void kernel_launch(void* const* d_in, const int* in_sizes, int n_in,
                              void* d_out, int out_size, void* d_ws, size_t ws_size,
                              hipStream_t stream) {
    const int*   x     = (const int*)  d_in[0];   // [64,2048]
    const float* emb   = (const float*)d_in[1];   // [50000,300]
    const float* query = (const float*)d_in[2];   // [1,300]
    const float* Watt  = (const float*)d_in[3];   // [300,150]
    const float* Wout  = (const float*)d_in[4];   // [600,34]
    const float* bias  = (const float*)d_in[5];   // [34]
    float* out = (float*)d_out;                   // [64,34]

    // ws layout: ebf (50000*320 ushorts = 32 MB, 16B-aligned at base),
    // then fp32 buffers. Total ~33.5 MB.
    unsigned short* ebf = (unsigned short*)d_ws;
    float* fbase  = (float*)((char*)d_ws + (size_t)50000 * EP * sizeof(unsigned short));
    float* qpad   = fbase;                         // 320
    float* h_part = qpad + EP;                     // 64*16*300 = 307200
    float* l_part = h_part + (size_t)B_ * NCHUNK * E_;  // 1024
    float* h1     = l_part + B_ * NCHUNK;          // 19200
    float* v2     = h1 + B_ * E_;                  // 64*320 = 20480

    dim3 grid(NCHUNK, B_), blk(256);

    conv_bf16<<<3126, 320, 0, stream>>>(emb, query, ebf, qpad);
    // Stage 1: padded pre-scaled query, stride 0
    attn_bf16<<<grid, blk, 0, stream>>>(x, ebf, qpad, 0, h_part, l_part);
    combine_qv<<<B_, 320, 0, stream>>>(h_part, l_part, Watt, h1, v2);
    // Stage 2: per-b padded query v2, stride EP
    attn_bf16<<<grid, blk, 0, stream>>>(x, ebf, v2, EP, h_part, l_part);
    combine_scores<<<B_, 320, 0, stream>>>(h_part, l_part, h1, Wout, bias, out);
}